// Round 7
// baseline (360.622 us; speedup 1.0000x reference)
//
#include <hip/hip_runtime.h>
#include <math.h>

typedef unsigned short u16;
typedef unsigned int   u32;
typedef short s16x8 __attribute__((ext_vector_type(8)));
typedef float f32x4 __attribute__((ext_vector_type(4)));

#define N_TOK 2048
#define DIM   512
#define HID   2048
#define NE    16
#define NG    4
#define EPG   4
#define MAXT  2048

#define BM 64
#define BN 128
#define BK 64

// ---- workspace layout (bytes) ----
#define WS_CNT    0                              // 16 ints
#define WS_OFF    128                            // 17 ints
#define WS_TOKIDX 256                            // 16*2048 ints
#define WS_TW     (WS_TOKIDX + NE*MAXT*4)        // twT[e][t]: 16*2048 f32
#define WS_XB     (WS_TW + N_TOK*NE*4)           // 2048*512 u16 (bf16 x)
#define WS_HBUF   (WS_XB + (size_t)N_TOK*DIM*2)  // 8192*2048 u16
#define WS_W1T    (WS_HBUF + (size_t)8192*HID*2) // 16*2048*512 u16 (bf16 W1^T [e][n][k])
#define WS_W3T    (WS_W1T + (size_t)NE*HID*DIM*2)
#define WS_W2T    (WS_W3T + (size_t)NE*HID*DIM*2) // 16*512*2048 u16 (bf16 W2^T [e][n][k])

__device__ __forceinline__ int* ws_i32(void* ws, size_t off) { return (int*)((char*)ws + off); }

__device__ __forceinline__ u16 f2b(float f) {   // fp32 -> bf16 RNE
    union { float f; u32 i; } v; v.f = f;
    u32 b = v.i;
    u32 r = b + 0x7FFFu + ((b >> 16) & 1u);
    return (u16)(r >> 16);
}

// async global->LDS, 16B/lane; LDS side is wave-uniform base + lane*16
__device__ __forceinline__ void gl_lds16(const u16* g, u16* l) {
    __builtin_amdgcn_global_load_lds((const __attribute__((address_space(1))) void*)g,
                                     (__attribute__((address_space(3))) void*)l, 16, 0, 0);
}

// ---------------- routing: 4 waves/block, one wave per token; NO atomics ----------------
__global__ __launch_bounds__(256) void routing_kernel(
    const float* __restrict__ x, const float* __restrict__ Wr, const float* __restrict__ br,
    const float* __restrict__ Wgate, const float* __restrict__ bgate, void* ws)
{
    int tid = threadIdx.x;
    int t = blockIdx.x * 4 + (tid >> 6);
    int lane = tid & 63;

    float xl[8];
    {
        const float4* xr = (const float4*)(x + (size_t)t*DIM + lane*8);
        float4 a = xr[0], b = xr[1];
        xl[0]=a.x; xl[1]=a.y; xl[2]=a.z; xl[3]=a.w;
        xl[4]=b.x; xl[5]=b.y; xl[6]=b.z; xl[7]=b.w;
    }

    {
        union { u16 h[8]; uint4 q; } pk;
        #pragma unroll
        for (int i = 0; i < 8; i++) pk.h[i] = f2b(xl[i]);
        u16* xb = (u16*)((char*)ws + WS_XB);
        *(uint4*)(xb + (size_t)t*DIM + lane*8) = pk.q;
    }

    float gl[NG] = {0.f,0.f,0.f,0.f};
    float el[NE];
    #pragma unroll
    for (int e = 0; e < NE; e++) el[e] = 0.f;

    {
        const float4* Wr4 = (const float4*)Wr;
        #pragma unroll
        for (int c = 0; c < 8; c++) {
            float4 w = Wr4[lane*8 + c];
            gl[0] += xl[c]*w.x; gl[1] += xl[c]*w.y;
            gl[2] += xl[c]*w.z; gl[3] += xl[c]*w.w;
        }
    }
    {
        const float4* Wg4 = (const float4*)Wgate;
        #pragma unroll
        for (int g = 0; g < NG; g++) {
            #pragma unroll
            for (int c = 0; c < 8; c++) {
                float4 w = Wg4[(size_t)g*DIM + lane*8 + c];
                el[g*4+0] += xl[c]*w.x; el[g*4+1] += xl[c]*w.y;
                el[g*4+2] += xl[c]*w.z; el[g*4+3] += xl[c]*w.w;
            }
        }
    }

    #pragma unroll
    for (int g = 0; g < NG; g++)
        #pragma unroll
        for (int s = 32; s; s >>= 1) gl[g] += __shfl_xor(gl[g], s);
    #pragma unroll
    for (int e = 0; e < NE; e++)
        #pragma unroll
        for (int s = 32; s; s >>= 1) el[e] += __shfl_xor(el[e], s);

    if (lane != 0) return;

    float gp[NG];
    float mx = -1e30f;
    #pragma unroll
    for (int g = 0; g < NG; g++) { gl[g] += br[g]; mx = fmaxf(mx, gl[g]); }
    float sum = 0.f;
    #pragma unroll
    for (int g = 0; g < NG; g++) { gp[g] = expf(gl[g] - mx); sum += gp[g]; }
    #pragma unroll
    for (int g = 0; g < NG; g++) gp[g] /= sum;

    int i0 = 0;
    #pragma unroll
    for (int g = 1; g < NG; g++) if (gp[g] > gp[i0]) i0 = g;
    int i1 = -1;
    #pragma unroll
    for (int g = 0; g < NG; g++) { if (g == i0) continue; if (i1 < 0 || gp[g] > gp[i1]) i1 = g; }

    bool act1 = (gp[i0] + gp[i1]) <= 0.9f;
    float mp0 = gp[i0], mp1 = act1 ? gp[i1] : 0.f;
    float inv = 1.f / (mp0 + mp1 + 1e-9f);
    float wg[NG] = {0.f,0.f,0.f,0.f};
    wg[i0] = mp0 * inv;
    wg[i1] = mp1 * inv;

    float tw[NE];
    #pragma unroll
    for (int g = 0; g < NG; g++) {
        float ep[EPG];
        float emx = -1e30f;
        #pragma unroll
        for (int j = 0; j < EPG; j++) {
            float v = el[g*4 + j] + bgate[g*4 + j];
            ep[j] = v; emx = fmaxf(emx, v);
        }
        float es = 0.f;
        #pragma unroll
        for (int j = 0; j < EPG; j++) { ep[j] = expf(ep[j] - emx); es += ep[j]; }
        #pragma unroll
        for (int j = 0; j < EPG; j++) ep[j] /= es;

        int j0 = 0;
        #pragma unroll
        for (int j = 1; j < EPG; j++) if (ep[j] > ep[j0]) j0 = j;
        int j1 = -1;
        #pragma unroll
        for (int j = 0; j < EPG; j++) { if (j == j0) continue; if (j1 < 0 || ep[j] > ep[j1]) j1 = j; }

        bool ea1 = (ep[j0] + ep[j1]) <= 0.9f;
        float e0 = ep[j0], e1 = ea1 ? ep[j1] : 0.f;
        float einv = 1.f / (e0 + e1 + 1e-9f);
        float we[EPG] = {0.f,0.f,0.f,0.f};
        we[j0] = e0 * einv;
        we[j1] = e1 * einv;
        #pragma unroll
        for (int j = 0; j < EPG; j++) tw[g*4 + j] = wg[g] * we[j] * 0.5f;   // SCALE = 1/sqrt(4)
    }

    float* twT = (float*)((char*)ws + WS_TW);
    #pragma unroll
    for (int e = 0; e < NE; e++) twT[(size_t)e*N_TOK + t] = tw[e];
}

// ---------------- expert lists + scan merged: 16 waves, ballot compaction ----------------
__global__ __launch_bounds__(1024) void expert_scan_kernel(void* ws)
{
    int tid = threadIdx.x;
    int e = tid >> 6, lane = tid & 63;
    const float* twT = (const float*)((char*)ws + WS_TW) + (size_t)e*N_TOK;
    int* tok = ws_i32(ws, WS_TOKIDX) + e*MAXT;
    __shared__ int scnt[NE];

    float v[32];
    #pragma unroll
    for (int r = 0; r < 32; r++) v[r] = twT[r*64 + lane];

    unsigned long long lanemask = (1ull << lane) - 1ull;
    int base = 0;
    #pragma unroll
    for (int r = 0; r < 32; r++) {
        bool a = v[r] > 0.f;
        unsigned long long m = __ballot(a);
        if (a) tok[base + __popcll(m & lanemask)] = r*64 + lane;
        base += __popcll(m);
    }
    if (lane == 0) scnt[e] = base;
    __syncthreads();
    if (tid == 0) {
        int* cnt = ws_i32(ws, WS_CNT);
        int* off = ws_i32(ws, WS_OFF);
        int s = 0;
        for (int i = 0; i < NE; i++) { cnt[i] = scnt[i]; off[i] = s; s += scnt[i]; }
        off[NE] = s;
    }
}

// ---- convert+transpose: fp32 [e][K][N] -> bf16 [e][N][K], 4x4 register micro-transpose ----
// LDS tile T[n][64] u16, unpadded (row = 128B), 8B-chunk XOR swizzle: phys = chunk ^ ((n>>2 & 7)<<1).
// Writes: b64, 2-way bank alias (free, m136). Reads: b128 rows.
__global__ __launch_bounds__(256) void transpose_all_kernel(
    const float* __restrict__ W1, const float* __restrict__ W3,
    const float* __restrict__ W2, void* ws)
{
    int z = blockIdx.z;
    int mat = z >> 4, e = z & 15;
    const float* src; u16* dst; int K, N, k0, n0;
    if (mat == 0)      { src = W1; dst = (u16*)((char*)ws + WS_W1T); K = DIM; N = HID; n0 = blockIdx.x*64; k0 = blockIdx.y*64; }
    else if (mat == 1) { src = W3; dst = (u16*)((char*)ws + WS_W3T); K = DIM; N = HID; n0 = blockIdx.x*64; k0 = blockIdx.y*64; }
    else               { src = W2; dst = (u16*)((char*)ws + WS_W2T); K = HID; N = DIM; k0 = blockIdx.x*64; n0 = blockIdx.y*64; }

    const float* s = src + (size_t)e*K*N;
    u16* d = dst + (size_t)e*N*K;

    __shared__ u16 T[64*64];
    int tid = threadIdx.x;
    int j = tid & 15, i = tid >> 4;     // j: n-micro (coalesced), i: k-micro

    {
        const float* base = s + (size_t)(k0 + 4*i)*N + n0 + 4*j;
        float4 v0 = *(const float4*)(base);
        float4 v1 = *(const float4*)(base + N);
        float4 v2 = *(const float4*)(base + 2*N);
        float4 v3 = *(const float4*)(base + 3*N);
        int swz = (j & 7) << 1;                       // ((n>>2)&7)<<1, n=4j+c
        int pc = 4 * (i ^ swz);                       // phys chunk offset in u16
        union { u16 h[4]; uint2 q; } p;
        p.h[0]=f2b(v0.x); p.h[1]=f2b(v1.x); p.h[2]=f2b(v2.x); p.h[3]=f2b(v3.x);
        *(uint2*)(&T[(4*j+0)*64 + pc]) = p.q;
        p.h[0]=f2b(v0.y); p.h[1]=f2b(v1.y); p.h[2]=f2b(v2.y); p.h[3]=f2b(v3.y);
        *(uint2*)(&T[(4*j+1)*64 + pc]) = p.q;
        p.h[0]=f2b(v0.z); p.h[1]=f2b(v1.z); p.h[2]=f2b(v2.z); p.h[3]=f2b(v3.z);
        *(uint2*)(&T[(4*j+2)*64 + pc]) = p.q;
        p.h[0]=f2b(v0.w); p.h[1]=f2b(v1.w); p.h[2]=f2b(v2.w); p.h[3]=f2b(v3.w);
        *(uint2*)(&T[(4*j+3)*64 + pc]) = p.q;
    }
    __syncthreads();
    #pragma unroll
    for (int it = 0; it < 2; it++) {
        int idx = tid + it*256;               // 512 b128 reads/stores (64 n-rows x 8)
        int nr = idx >> 3, sg = idx & 7;
        int p = (2*sg) ^ (((nr >> 2) & 7) << 1);
        *(s16x8*)(d + (size_t)(n0+nr)*K + k0 + sg*8) = *(const s16x8*)(&T[nr*64 + 4*p]);
    }
}

// ---------------- GEMM1: hbuf = bf16( silu(X W1) * (X W3) ), async-LDS staging ----------------
__global__ __launch_bounds__(256) void gemm1_fast(void* ws)
{
    int e  = blockIdx.z;
    const int* cnt = ws_i32(ws, WS_CNT);
    int ce = cnt[e];
    int m0 = blockIdx.y * BM;
    if (m0 >= ce) return;
    int n0 = blockIdx.x * BN;

    const int* off = ws_i32(ws, WS_OFF);
    const int* tok = ws_i32(ws, WS_TOKIDX) + e*MAXT;
    const u16* xb  = (const u16*)((char*)ws + WS_XB);
    const u16* W1T = (const u16*)((char*)ws + WS_W1T) + (size_t)e*HID*DIM;  // [n][k]
    const u16* W3T = (const u16*)((char*)ws + WS_W3T) + (size_t)e*HID*DIM;
    u16* hbuf = (u16*)((char*)ws + WS_HBUF);
    int obase = off[e] + m0;

    __shared__ u16 As[BM*BK];        // swizzled [m][k]
    __shared__ u16 Bs0[BN*BK];       // swizzled [n][k]
    __shared__ u16 Bs1[BN*BK];
    __shared__ int rowtok[BM];

    int tid = threadIdx.x;
    if (tid < BM) {
        int m = m0 + tid;
        rowtok[tid] = tok[m < ce ? m : (ce - 1)];
    }
    __syncthreads();

    int wave = tid >> 6, lane = tid & 63;
    int quad = lane >> 4, l16 = lane & 15;
    int swz  = l16 & 7;
    int r8 = lane >> 3, sg = lane & 7;
    int swk = ((sg ^ r8) << 3);      // swizzle folded into global k-offset

    const u16* arow0 = xb + (size_t)rowtok[wave*16 + r8]*DIM + swk;
    const u16* arow1 = xb + (size_t)rowtok[wave*16 + 8 + r8]*DIM + swk;
    const u16* b1row[4]; const u16* b3row[4];
    #pragma unroll
    for (int i = 0; i < 4; i++) {
        size_t nr = (size_t)(n0 + wave*32 + i*8 + r8)*DIM + swk;
        b1row[i] = W1T + nr;
        b3row[i] = W3T + nr;
    }

    f32x4 acc1[4][2], acc3[4][2];
    #pragma unroll
    for (int mt = 0; mt < 4; mt++)
        #pragma unroll
        for (int nt = 0; nt < 2; nt++) {
            acc1[mt][nt] = (f32x4){0.f,0.f,0.f,0.f};
            acc3[mt][nt] = (f32x4){0.f,0.f,0.f,0.f};
        }

    for (int k0 = 0; k0 < DIM; k0 += BK) {
        gl_lds16(arow0 + k0, &As[(wave*16)*BK]);
        gl_lds16(arow1 + k0, &As[(wave*16 + 8)*BK]);
        #pragma unroll
        for (int i = 0; i < 4; i++) {
            gl_lds16(b1row[i] + k0, &Bs0[(wave*32 + i*8)*BK]);
            gl_lds16(b3row[i] + k0, &Bs1[(wave*32 + i*8)*BK]);
        }
        __syncthreads();

        #pragma unroll
        for (int kk = 0; kk < BK; kk += 32) {
            int jj = (kk >> 3) + quad;
            int so = ((jj ^ swz) << 3);
            s16x8 af[4];
            #pragma unroll
            for (int mt = 0; mt < 4; mt++)
                af[mt] = *(const s16x8*)(&As[(mt*16 + l16)*BK + so]);
            #pragma unroll
            for (int nt = 0; nt < 2; nt++) {
                int n = wave*32 + nt*16 + l16;
                s16x8 b1 = *(const s16x8*)(&Bs0[n*BK + so]);
                s16x8 b3 = *(const s16x8*)(&Bs1[n*BK + so]);
                #pragma unroll
                for (int mt = 0; mt < 4; mt++) {
                    acc1[mt][nt] = __builtin_amdgcn_mfma_f32_16x16x32_bf16(af[mt], b1, acc1[mt][nt], 0, 0, 0);
                    acc3[mt][nt] = __builtin_amdgcn_mfma_f32_16x16x32_bf16(af[mt], b3, acc3[mt][nt], 0, 0, 0);
                }
            }
        }
        __syncthreads();
    }

    #pragma unroll
    for (int mt = 0; mt < 4; mt++) {
        #pragma unroll
        for (int r = 0; r < 4; r++) {
            int row = mt*16 + quad*4 + r;
            if (m0 + row < ce) {
                #pragma unroll
                for (int nt = 0; nt < 2; nt++) {
                    float a = acc1[mt][nt][r];
                    float b = acc3[mt][nt][r];
                    float h = (a / (1.f + expf(-a))) * b;
                    int col = wave*32 + nt*16 + l16;
                    hbuf[(size_t)(obase + row)*HID + n0 + col] = f2b(h);
                }
            }
        }
    }
}

// ---------------- GEMM2: out += tw * (h W2), async-LDS staging ----------------
__global__ __launch_bounds__(256) void gemm2_fast(void* ws, float* __restrict__ out)
{
    int e  = blockIdx.z;
    const int* cnt = ws_i32(ws, WS_CNT);
    int ce = cnt[e];
    int m0 = blockIdx.y * BM;
    if (m0 >= ce) return;
    int n0 = blockIdx.x * BN;

    const int* off = ws_i32(ws, WS_OFF);
    const int* tok = ws_i32(ws, WS_TOKIDX) + e*MAXT;
    const float* twT = (const float*)((char*)ws + WS_TW);
    const u16* hbuf = (const u16*)((char*)ws + WS_HBUF);
    const u16* W2T = (const u16*)((char*)ws + WS_W2T) + (size_t)e*DIM*HID;  // [n=512][k=2048]
    int abase = off[e] + m0;
    int total = off[NE];

    __shared__ u16 As[BM*BK];
    __shared__ u16 Bs[BN*BK];

    int tid = threadIdx.x;
    int wave = tid >> 6, lane = tid & 63;
    int quad = lane >> 4, l16 = lane & 15;
    int swz  = l16 & 7;
    int r8 = lane >> 3, sg = lane & 7;
    int swk = ((sg ^ r8) << 3);

    int ar0 = abase + wave*16 + r8;      if (ar0 > total - 1) ar0 = total - 1;
    int ar1 = abase + wave*16 + 8 + r8;  if (ar1 > total - 1) ar1 = total - 1;
    const u16* arow0 = hbuf + (size_t)ar0*HID + swk;
    const u16* arow1 = hbuf + (size_t)ar1*HID + swk;
    const u16* brow[4];
    #pragma unroll
    for (int i = 0; i < 4; i++)
        brow[i] = W2T + (size_t)(n0 + wave*32 + i*8 + r8)*HID + swk;

    f32x4 acc[4][2];
    #pragma unroll
    for (int mt = 0; mt < 4; mt++)
        #pragma unroll
        for (int nt = 0; nt < 2; nt++) acc[mt][nt] = (f32x4){0.f,0.f,0.f,0.f};

    for (int k0 = 0; k0 < HID; k0 += BK) {
        gl_lds16(arow0 + k0, &As[(wave*16)*BK]);
        gl_lds16(arow1 + k0, &As[(wave*16 + 8)*BK]);
        #pragma unroll
        for (int i = 0; i < 4; i++)
            gl_lds16(brow[i] + k0, &Bs[(wave*32 + i*8)*BK]);
        __syncthreads();

        #pragma unroll
        for (int kk = 0; kk < BK; kk += 32) {
            int jj = (kk >> 3) + quad;
            int so = ((jj ^ swz) << 3);
            s16x8 af[4];
            #pragma unroll
            for (int mt = 0; mt < 4; mt++)
                af[mt] = *(const s16x8*)(&As[(mt*16 + l16)*BK + so]);
            #pragma unroll
            for (int nt = 0; nt < 2; nt++) {
                int n = wave*32 + nt*16 + l16;
                s16x8 bfr = *(const s16x8*)(&Bs[n*BK + so]);
                #pragma unroll
                for (int mt = 0; mt < 4; mt++)
                    acc[mt][nt] = __builtin_amdgcn_mfma_f32_16x16x32_bf16(af[mt], bfr, acc[mt][nt], 0, 0, 0);
            }
        }
        __syncthreads();
    }

    #pragma unroll
    for (int mt = 0; mt < 4; mt++) {
        #pragma unroll
        for (int r = 0; r < 4; r++) {
            int row = mt*16 + quad*4 + r;
            if (m0 + row < ce) {
                int t = tok[m0 + row];
                float s = twT[(size_t)e*N_TOK + t];
                #pragma unroll
                for (int nt = 0; nt < 2; nt++) {
                    int col = wave*32 + nt*16 + l16;
                    atomicAdd(out + (size_t)t*DIM + n0 + col, acc[mt][nt][r] * s);
                }
            }
        }
    }
}

extern "C" void kernel_launch(void* const* d_in, const int* in_sizes, int n_in,
                              void* d_out, int out_size, void* d_ws, size_t ws_size,
                              hipStream_t stream)
{
    const float* x     = (const float*)d_in[0];
    const float* Wr    = (const float*)d_in[1];
    const float* br    = (const float*)d_in[2];
    const float* Wgate = (const float*)d_in[3];
    const float* bgate = (const float*)d_in[4];
    const float* W1    = (const float*)d_in[5];
    const float* W3    = (const float*)d_in[6];
    const float* W2    = (const float*)d_in[7];
    float* out = (float*)d_out;

    hipMemsetAsync(d_out, 0, (size_t)out_size*sizeof(float), stream);

    transpose_all_kernel<<<dim3(32, 8, 48), 256, 0, stream>>>(W1, W3, W2, d_ws);
    routing_kernel<<<N_TOK/4, 256, 0, stream>>>(x, Wr, br, Wgate, bgate, d_ws);
    expert_scan_kernel<<<1, 1024, 0, stream>>>(d_ws);
    gemm1_fast<<<dim3(HID/BN, N_TOK/BM, NE), 256, 0, stream>>>(d_ws);
    gemm2_fast<<<dim3(DIM/BN, N_TOK/BM, NE), 256, 0, stream>>>(d_ws, out);
}

// Round 8
// 358.957 us; speedup vs baseline: 1.0046x; 1.0046x over previous
//
#include <hip/hip_runtime.h>
#include <math.h>

typedef unsigned short u16;
typedef unsigned int   u32;
typedef short s16x8 __attribute__((ext_vector_type(8)));
typedef float f32x4 __attribute__((ext_vector_type(4)));

#define N_TOK 2048
#define DIM   512
#define HID   2048
#define NE    16
#define NG    4
#define EPG   4
#define MAXT  2048

#define BM 64
#define BN 128
#define BK 64

// ---- workspace layout (bytes) ----
#define WS_CNT    0                              // 16 ints
#define WS_OFF    128                            // 17 ints
#define WS_TOKIDX 256                            // 16*2048 ints
#define WS_TW     (WS_TOKIDX + NE*MAXT*4)        // twT[e][t]: 16*2048 f32
#define WS_XB     (WS_TW + N_TOK*NE*4)           // 2048*512 u16 (bf16 x)
#define WS_HBUF   (WS_XB + (size_t)N_TOK*DIM*2)  // 8192*2048 u16
#define WS_W1T    (WS_HBUF + (size_t)8192*HID*2) // 16*2048*512 u16 (bf16 W1^T [e][n][k])
#define WS_W3T    (WS_W1T + (size_t)NE*HID*DIM*2)
#define WS_W2T    (WS_W3T + (size_t)NE*HID*DIM*2) // 16*512*2048 u16 (bf16 W2^T [e][n][k])
#define WS_SLOT   (WS_W2T + (size_t)NE*DIM*HID*2) // slot_of[e][t]: 16*2048 ints
// buf2 (8192*512 f32 = 16.8 MB) aliases W1T: W1T is dead once gemm1 completes,
// buf2 is written by gemm2 (after gemm1) and read by gather. Safe within one call
// and across graph replays (transpose rewrites W1T first each call).
#define WS_BUF2   WS_W1T

__device__ __forceinline__ int* ws_i32(void* ws, size_t off) { return (int*)((char*)ws + off); }

__device__ __forceinline__ u16 f2b(float f) {   // fp32 -> bf16 RNE
    union { float f; u32 i; } v; v.f = f;
    u32 b = v.i;
    u32 r = b + 0x7FFFu + ((b >> 16) & 1u);
    return (u16)(r >> 16);
}

// async global->LDS, 16B/lane; LDS side is wave-uniform base + lane*16
__device__ __forceinline__ void gl_lds16(const u16* g, u16* l) {
    __builtin_amdgcn_global_load_lds((const __attribute__((address_space(1))) void*)g,
                                     (__attribute__((address_space(3))) void*)l, 16, 0, 0);
}

// ---------------- routing: 4 waves/block, one wave per token; NO atomics ----------------
__global__ __launch_bounds__(256) void routing_kernel(
    const float* __restrict__ x, const float* __restrict__ Wr, const float* __restrict__ br,
    const float* __restrict__ Wgate, const float* __restrict__ bgate, void* ws)
{
    int tid = threadIdx.x;
    int t = blockIdx.x * 4 + (tid >> 6);
    int lane = tid & 63;

    float xl[8];
    {
        const float4* xr = (const float4*)(x + (size_t)t*DIM + lane*8);
        float4 a = xr[0], b = xr[1];
        xl[0]=a.x; xl[1]=a.y; xl[2]=a.z; xl[3]=a.w;
        xl[4]=b.x; xl[5]=b.y; xl[6]=b.z; xl[7]=b.w;
    }

    {
        union { u16 h[8]; uint4 q; } pk;
        #pragma unroll
        for (int i = 0; i < 8; i++) pk.h[i] = f2b(xl[i]);
        u16* xb = (u16*)((char*)ws + WS_XB);
        *(uint4*)(xb + (size_t)t*DIM + lane*8) = pk.q;
    }

    float gl[NG] = {0.f,0.f,0.f,0.f};
    float el[NE];
    #pragma unroll
    for (int e = 0; e < NE; e++) el[e] = 0.f;

    {
        const float4* Wr4 = (const float4*)Wr;
        #pragma unroll
        for (int c = 0; c < 8; c++) {
            float4 w = Wr4[lane*8 + c];
            gl[0] += xl[c]*w.x; gl[1] += xl[c]*w.y;
            gl[2] += xl[c]*w.z; gl[3] += xl[c]*w.w;
        }
    }
    {
        const float4* Wg4 = (const float4*)Wgate;
        #pragma unroll
        for (int g = 0; g < NG; g++) {
            #pragma unroll
            for (int c = 0; c < 8; c++) {
                float4 w = Wg4[(size_t)g*DIM + lane*8 + c];
                el[g*4+0] += xl[c]*w.x; el[g*4+1] += xl[c]*w.y;
                el[g*4+2] += xl[c]*w.z; el[g*4+3] += xl[c]*w.w;
            }
        }
    }

    #pragma unroll
    for (int g = 0; g < NG; g++)
        #pragma unroll
        for (int s = 32; s; s >>= 1) gl[g] += __shfl_xor(gl[g], s);
    #pragma unroll
    for (int e = 0; e < NE; e++)
        #pragma unroll
        for (int s = 32; s; s >>= 1) el[e] += __shfl_xor(el[e], s);

    if (lane != 0) return;

    float gp[NG];
    float mx = -1e30f;
    #pragma unroll
    for (int g = 0; g < NG; g++) { gl[g] += br[g]; mx = fmaxf(mx, gl[g]); }
    float sum = 0.f;
    #pragma unroll
    for (int g = 0; g < NG; g++) { gp[g] = expf(gl[g] - mx); sum += gp[g]; }
    #pragma unroll
    for (int g = 0; g < NG; g++) gp[g] /= sum;

    int i0 = 0;
    #pragma unroll
    for (int g = 1; g < NG; g++) if (gp[g] > gp[i0]) i0 = g;
    int i1 = -1;
    #pragma unroll
    for (int g = 0; g < NG; g++) { if (g == i0) continue; if (i1 < 0 || gp[g] > gp[i1]) i1 = g; }

    bool act1 = (gp[i0] + gp[i1]) <= 0.9f;
    float mp0 = gp[i0], mp1 = act1 ? gp[i1] : 0.f;
    float inv = 1.f / (mp0 + mp1 + 1e-9f);
    float wg[NG] = {0.f,0.f,0.f,0.f};
    wg[i0] = mp0 * inv;
    wg[i1] = mp1 * inv;

    float tw[NE];
    #pragma unroll
    for (int g = 0; g < NG; g++) {
        float ep[EPG];
        float emx = -1e30f;
        #pragma unroll
        for (int j = 0; j < EPG; j++) {
            float v = el[g*4 + j] + bgate[g*4 + j];
            ep[j] = v; emx = fmaxf(emx, v);
        }
        float es = 0.f;
        #pragma unroll
        for (int j = 0; j < EPG; j++) { ep[j] = expf(ep[j] - emx); es += ep[j]; }
        #pragma unroll
        for (int j = 0; j < EPG; j++) ep[j] /= es;

        int j0 = 0;
        #pragma unroll
        for (int j = 1; j < EPG; j++) if (ep[j] > ep[j0]) j0 = j;
        int j1 = -1;
        #pragma unroll
        for (int j = 0; j < EPG; j++) { if (j == j0) continue; if (j1 < 0 || ep[j] > ep[j1]) j1 = j; }

        bool ea1 = (ep[j0] + ep[j1]) <= 0.9f;
        float e0 = ep[j0], e1 = ea1 ? ep[j1] : 0.f;
        float einv = 1.f / (e0 + e1 + 1e-9f);
        float we[EPG] = {0.f,0.f,0.f,0.f};
        we[j0] = e0 * einv;
        we[j1] = e1 * einv;
        #pragma unroll
        for (int j = 0; j < EPG; j++) tw[g*4 + j] = wg[g] * we[j] * 0.5f;   // SCALE = 1/sqrt(4)
    }

    float* twT = (float*)((char*)ws + WS_TW);
    #pragma unroll
    for (int e = 0; e < NE; e++) twT[(size_t)e*N_TOK + t] = tw[e];
}

// ---- expert lists + scan + slot map: 16 waves, two ballot passes, no atomics ----
__global__ __launch_bounds__(1024) void expert_scan_kernel(void* ws)
{
    int tid = threadIdx.x;
    int e = tid >> 6, lane = tid & 63;
    const float* twT = (const float*)((char*)ws + WS_TW) + (size_t)e*N_TOK;
    int* tok = ws_i32(ws, WS_TOKIDX) + e*MAXT;
    __shared__ int scnt[NE];
    __shared__ int soff[NE+1];

    float v[32];
    #pragma unroll
    for (int r = 0; r < 32; r++) v[r] = twT[r*64 + lane];

    unsigned long long lanemask = (1ull << lane) - 1ull;
    int base = 0;
    #pragma unroll
    for (int r = 0; r < 32; r++) {
        bool a = v[r] > 0.f;
        unsigned long long m = __ballot(a);
        if (a) tok[base + __popcll(m & lanemask)] = r*64 + lane;
        base += __popcll(m);
    }
    if (lane == 0) scnt[e] = base;
    __syncthreads();
    if (tid == 0) {
        int* cnt = ws_i32(ws, WS_CNT);
        int* off = ws_i32(ws, WS_OFF);
        int s = 0;
        for (int i = 0; i < NE; i++) { cnt[i] = scnt[i]; off[i] = s; soff[i] = s; s += scnt[i]; }
        off[NE] = s; soff[NE] = s;
    }
    __syncthreads();

    // pass 2: global slot per (e,t), -1 if inactive
    int* slot_of = ws_i32(ws, WS_SLOT) + e*N_TOK;
    int base2 = soff[e];
    #pragma unroll
    for (int r = 0; r < 32; r++) {
        bool a = v[r] > 0.f;
        unsigned long long m = __ballot(a);
        int pre = __popcll(m & lanemask);
        slot_of[r*64 + lane] = a ? (base2 + pre) : -1;
        base2 += __popcll(m);
    }
}

// ---- convert+transpose: fp32 [e][K][N] -> bf16 [e][N][K] ----
// 256k x 128n tiles, 1024 threads, 4x4 register micro-transpose.
// Global: 512B-contiguous read AND write segments (vs 256/128B in r7 — HBM-efficiency fix).
// LDS T[128n][256k] u16, 8B-chunk XOR swizzle c' = c ^ ((n>>2 & 15)<<1): write alias 2-way (free),
// b128 reads stay pair-adjacent (swizzle even).
__global__ __launch_bounds__(1024) void transpose_all_kernel(
    const float* __restrict__ W1, const float* __restrict__ W3,
    const float* __restrict__ W2, void* ws)
{
    int z = blockIdx.z;
    int mat = z >> 4, e = z & 15;
    int tx = blockIdx.x;
    const float* src; u16* dst; int K, N, k0, n0;
    if (mat == 0)      { src = W1; dst = (u16*)((char*)ws + WS_W1T); K = DIM; N = HID; k0 = (tx>>4)*256; n0 = (tx&15)*128; }
    else if (mat == 1) { src = W3; dst = (u16*)((char*)ws + WS_W3T); K = DIM; N = HID; k0 = (tx>>4)*256; n0 = (tx&15)*128; }
    else               { src = W2; dst = (u16*)((char*)ws + WS_W2T); K = HID; N = DIM; k0 = (tx>>2)*256; n0 = (tx&3)*128; }

    const float* s = src + (size_t)e*K*N;
    u16* d = dst + (size_t)e*N*K;

    __shared__ u16 T[128*256];   // 64 KB
    int tid = threadIdx.x;
    int j = tid & 31, i0 = tid >> 5;    // j: n-micro (coalesced), i0: k-micro

    #pragma unroll
    for (int itk = 0; itk < 2; itk++) {
        int kb = 4*i0 + 128*itk;                      // k offset in tile (0..255)
        const float* base = s + (size_t)(k0 + kb)*N + n0 + 4*j;
        float4 v0 = *(const float4*)(base);
        float4 v1 = *(const float4*)(base + N);
        float4 v2 = *(const float4*)(base + 2*N);
        float4 v3 = *(const float4*)(base + 3*N);
        int c  = (kb >> 2);                           // logical 8B chunk (0..63)
        int pc = 4 * (c ^ ((j & 15) << 1));           // phys chunk offset in u16
        union { u16 h[4]; uint2 q; } p;
        p.h[0]=f2b(v0.x); p.h[1]=f2b(v1.x); p.h[2]=f2b(v2.x); p.h[3]=f2b(v3.x);
        *(uint2*)(&T[(4*j+0)*256 + pc]) = p.q;
        p.h[0]=f2b(v0.y); p.h[1]=f2b(v1.y); p.h[2]=f2b(v2.y); p.h[3]=f2b(v3.y);
        *(uint2*)(&T[(4*j+1)*256 + pc]) = p.q;
        p.h[0]=f2b(v0.z); p.h[1]=f2b(v1.z); p.h[2]=f2b(v2.z); p.h[3]=f2b(v3.z);
        *(uint2*)(&T[(4*j+2)*256 + pc]) = p.q;
        p.h[0]=f2b(v0.w); p.h[1]=f2b(v1.w); p.h[2]=f2b(v2.w); p.h[3]=f2b(v3.w);
        *(uint2*)(&T[(4*j+3)*256 + pc]) = p.q;
    }
    __syncthreads();
    #pragma unroll
    for (int it = 0; it < 4; it++) {
        int idx = tid + it*1024;                      // 4096 b128s (128 n-rows x 32)
        int nr = idx >> 5, sg = idx & 31;
        int cp = (2*sg) ^ (((nr >> 2) & 15) << 1);    // phys 8B-chunk of the pair
        *(s16x8*)(d + (size_t)(n0+nr)*K + k0 + sg*8) = *(const s16x8*)(&T[nr*256 + 4*cp]);
    }
}

// ---------------- GEMM1: hbuf = bf16( silu(X W1) * (X W3) ), async-LDS staging ----------------
__global__ __launch_bounds__(256) void gemm1_fast(void* ws)
{
    int e  = blockIdx.z;
    const int* cnt = ws_i32(ws, WS_CNT);
    int ce = cnt[e];
    int m0 = blockIdx.y * BM;
    if (m0 >= ce) return;
    int n0 = blockIdx.x * BN;

    const int* off = ws_i32(ws, WS_OFF);
    const int* tok = ws_i32(ws, WS_TOKIDX) + e*MAXT;
    const u16* xb  = (const u16*)((char*)ws + WS_XB);
    const u16* W1T = (const u16*)((char*)ws + WS_W1T) + (size_t)e*HID*DIM;  // [n][k]
    const u16* W3T = (const u16*)((char*)ws + WS_W3T) + (size_t)e*HID*DIM;
    u16* hbuf = (u16*)((char*)ws + WS_HBUF);
    int obase = off[e] + m0;

    __shared__ u16 As[BM*BK];        // swizzled [m][k]
    __shared__ u16 Bs0[BN*BK];       // swizzled [n][k]
    __shared__ u16 Bs1[BN*BK];
    __shared__ int rowtok[BM];

    int tid = threadIdx.x;
    if (tid < BM) {
        int m = m0 + tid;
        rowtok[tid] = tok[m < ce ? m : (ce - 1)];
    }
    __syncthreads();

    int wave = tid >> 6, lane = tid & 63;
    int quad = lane >> 4, l16 = lane & 15;
    int swz  = l16 & 7;
    int r8 = lane >> 3, sg = lane & 7;
    int swk = ((sg ^ r8) << 3);      // swizzle folded into global k-offset

    const u16* arow0 = xb + (size_t)rowtok[wave*16 + r8]*DIM + swk;
    const u16* arow1 = xb + (size_t)rowtok[wave*16 + 8 + r8]*DIM + swk;
    const u16* b1row[4]; const u16* b3row[4];
    #pragma unroll
    for (int i = 0; i < 4; i++) {
        size_t nr = (size_t)(n0 + wave*32 + i*8 + r8)*DIM + swk;
        b1row[i] = W1T + nr;
        b3row[i] = W3T + nr;
    }

    f32x4 acc1[4][2], acc3[4][2];
    #pragma unroll
    for (int mt = 0; mt < 4; mt++)
        #pragma unroll
        for (int nt = 0; nt < 2; nt++) {
            acc1[mt][nt] = (f32x4){0.f,0.f,0.f,0.f};
            acc3[mt][nt] = (f32x4){0.f,0.f,0.f,0.f};
        }

    for (int k0 = 0; k0 < DIM; k0 += BK) {
        gl_lds16(arow0 + k0, &As[(wave*16)*BK]);
        gl_lds16(arow1 + k0, &As[(wave*16 + 8)*BK]);
        #pragma unroll
        for (int i = 0; i < 4; i++) {
            gl_lds16(b1row[i] + k0, &Bs0[(wave*32 + i*8)*BK]);
            gl_lds16(b3row[i] + k0, &Bs1[(wave*32 + i*8)*BK]);
        }
        __syncthreads();

        #pragma unroll
        for (int kk = 0; kk < BK; kk += 32) {
            int jj = (kk >> 3) + quad;
            int so = ((jj ^ swz) << 3);
            s16x8 af[4];
            #pragma unroll
            for (int mt = 0; mt < 4; mt++)
                af[mt] = *(const s16x8*)(&As[(mt*16 + l16)*BK + so]);
            #pragma unroll
            for (int nt = 0; nt < 2; nt++) {
                int n = wave*32 + nt*16 + l16;
                s16x8 b1 = *(const s16x8*)(&Bs0[n*BK + so]);
                s16x8 b3 = *(const s16x8*)(&Bs1[n*BK + so]);
                #pragma unroll
                for (int mt = 0; mt < 4; mt++) {
                    acc1[mt][nt] = __builtin_amdgcn_mfma_f32_16x16x32_bf16(af[mt], b1, acc1[mt][nt], 0, 0, 0);
                    acc3[mt][nt] = __builtin_amdgcn_mfma_f32_16x16x32_bf16(af[mt], b3, acc3[mt][nt], 0, 0, 0);
                }
            }
        }
        __syncthreads();
    }

    #pragma unroll
    for (int mt = 0; mt < 4; mt++) {
        #pragma unroll
        for (int r = 0; r < 4; r++) {
            int row = mt*16 + quad*4 + r;
            if (m0 + row < ce) {
                #pragma unroll
                for (int nt = 0; nt < 2; nt++) {
                    float a = acc1[mt][nt][r];
                    float b = acc3[mt][nt][r];
                    float h = (a / (1.f + expf(-a))) * b;
                    int col = wave*32 + nt*16 + l16;
                    hbuf[(size_t)(obase + row)*HID + n0 + col] = f2b(h);
                }
            }
        }
    }
}

// ---------------- GEMM2: buf2 = tw * (h W2), plain stores (no atomics) ----------------
__global__ __launch_bounds__(256) void gemm2_fast(void* ws)
{
    int e  = blockIdx.z;
    const int* cnt = ws_i32(ws, WS_CNT);
    int ce = cnt[e];
    int m0 = blockIdx.y * BM;
    if (m0 >= ce) return;
    int n0 = blockIdx.x * BN;

    const int* off = ws_i32(ws, WS_OFF);
    const int* tok = ws_i32(ws, WS_TOKIDX) + e*MAXT;
    const float* twT = (const float*)((char*)ws + WS_TW);
    const u16* hbuf = (const u16*)((char*)ws + WS_HBUF);
    const u16* W2T = (const u16*)((char*)ws + WS_W2T) + (size_t)e*DIM*HID;  // [n=512][k=2048]
    float* buf2 = (float*)((char*)ws + WS_BUF2);
    int abase = off[e] + m0;
    int total = off[NE];

    __shared__ u16 As[BM*BK];
    __shared__ u16 Bs[BN*BK];

    int tid = threadIdx.x;
    int wave = tid >> 6, lane = tid & 63;
    int quad = lane >> 4, l16 = lane & 15;
    int swz  = l16 & 7;
    int r8 = lane >> 3, sg = lane & 7;
    int swk = ((sg ^ r8) << 3);

    int ar0 = abase + wave*16 + r8;      if (ar0 > total - 1) ar0 = total - 1;
    int ar1 = abase + wave*16 + 8 + r8;  if (ar1 > total - 1) ar1 = total - 1;
    const u16* arow0 = hbuf + (size_t)ar0*HID + swk;
    const u16* arow1 = hbuf + (size_t)ar1*HID + swk;
    const u16* brow[4];
    #pragma unroll
    for (int i = 0; i < 4; i++)
        brow[i] = W2T + (size_t)(n0 + wave*32 + i*8 + r8)*HID + swk;

    f32x4 acc[4][2];
    #pragma unroll
    for (int mt = 0; mt < 4; mt++)
        #pragma unroll
        for (int nt = 0; nt < 2; nt++) acc[mt][nt] = (f32x4){0.f,0.f,0.f,0.f};

    for (int k0 = 0; k0 < HID; k0 += BK) {
        gl_lds16(arow0 + k0, &As[(wave*16)*BK]);
        gl_lds16(arow1 + k0, &As[(wave*16 + 8)*BK]);
        #pragma unroll
        for (int i = 0; i < 4; i++)
            gl_lds16(brow[i] + k0, &Bs[(wave*32 + i*8)*BK]);
        __syncthreads();

        #pragma unroll
        for (int kk = 0; kk < BK; kk += 32) {
            int jj = (kk >> 3) + quad;
            int so = ((jj ^ swz) << 3);
            s16x8 af[4];
            #pragma unroll
            for (int mt = 0; mt < 4; mt++)
                af[mt] = *(const s16x8*)(&As[(mt*16 + l16)*BK + so]);
            #pragma unroll
            for (int nt = 0; nt < 2; nt++) {
                int n = wave*32 + nt*16 + l16;
                s16x8 bfr = *(const s16x8*)(&Bs[n*BK + so]);
                #pragma unroll
                for (int mt = 0; mt < 4; mt++)
                    acc[mt][nt] = __builtin_amdgcn_mfma_f32_16x16x32_bf16(af[mt], bfr, acc[mt][nt], 0, 0, 0);
            }
        }
        __syncthreads();
    }

    #pragma unroll
    for (int mt = 0; mt < 4; mt++) {
        #pragma unroll
        for (int r = 0; r < 4; r++) {
            int row = mt*16 + quad*4 + r;
            if (m0 + row < ce) {
                int t = tok[m0 + row];
                float s = twT[(size_t)e*N_TOK + t];
                #pragma unroll
                for (int nt = 0; nt < 2; nt++) {
                    int col = wave*32 + nt*16 + l16;
                    buf2[(size_t)(abase + row)*DIM + n0 + col] = acc[mt][nt][r] * s;
                }
            }
        }
    }
}

// ---------------- gather: out[t] = sum of buf2 rows for t's active experts ----------------
__global__ __launch_bounds__(128) void gather_kernel(void* ws, float* __restrict__ out)
{
    int t = blockIdx.x;
    int tid = threadIdx.x;
    const int* slot_of = ws_i32(ws, WS_SLOT);
    const float* buf2 = (const float*)((char*)ws + WS_BUF2);

    int d = tid * 4;
    float4 acc = {0.f, 0.f, 0.f, 0.f};
    #pragma unroll
    for (int e = 0; e < NE; e++) {
        int s = slot_of[e*N_TOK + t];      // wave-uniform per block
        if (s >= 0) {
            float4 v = *(const float4*)(buf2 + (size_t)s*DIM + d);
            acc.x += v.x; acc.y += v.y; acc.z += v.z; acc.w += v.w;
        }
    }
    *(float4*)(out + (size_t)t*DIM + d) = acc;
}

extern "C" void kernel_launch(void* const* d_in, const int* in_sizes, int n_in,
                              void* d_out, int out_size, void* d_ws, size_t ws_size,
                              hipStream_t stream)
{
    const float* x     = (const float*)d_in[0];
    const float* Wr    = (const float*)d_in[1];
    const float* br    = (const float*)d_in[2];
    const float* Wgate = (const float*)d_in[3];
    const float* bgate = (const float*)d_in[4];
    const float* W1    = (const float*)d_in[5];
    const float* W3    = (const float*)d_in[6];
    const float* W2    = (const float*)d_in[7];
    float* out = (float*)d_out;

    transpose_all_kernel<<<dim3(32, 1, 48), 1024, 0, stream>>>(W1, W3, W2, d_ws);
    routing_kernel<<<N_TOK/4, 256, 0, stream>>>(x, Wr, br, Wgate, bgate, d_ws);
    expert_scan_kernel<<<1, 1024, 0, stream>>>(d_ws);
    gemm1_fast<<<dim3(HID/BN, N_TOK/BM, NE), 256, 0, stream>>>(d_ws);
    gemm2_fast<<<dim3(DIM/BN, N_TOK/BM, NE), 256, 0, stream>>>(d_ws);
    gather_kernel<<<N_TOK, 128, 0, stream>>>(d_ws, out);
}